// Round 14
// baseline (106.932 us; speedup 1.0000x reference)
//
#include <hip/hip_runtime.h>
#include <math.h>

#define NB 32
#define NL 2048
#define NH 8
#define NE 64
#define NM 64
#define MRI 128          // 2*NM (re stacked over im)
#define BK 128           // K per chunk
#define NCH 16           // 2048 / BK

typedef __attribute__((ext_vector_type(8))) __bf16 bf16x8;
typedef __attribute__((ext_vector_type(2))) __bf16 bf16x2;
typedef __attribute__((ext_vector_type(8))) unsigned short us8;
typedef __attribute__((ext_vector_type(4))) unsigned short us4;
typedef __attribute__((ext_vector_type(4))) float f32x4;
typedef __attribute__((ext_vector_type(16))) float f32x16;

__device__ __forceinline__ unsigned short f2bf(float x) {
  unsigned int u = __builtin_bit_cast(unsigned int, x);
  u = (u + 0x7fffu + ((u >> 16) & 1u)) >> 16;
  return (unsigned short)u;
}
__device__ __forceinline__ float bf2f(unsigned short u) {
  return __builtin_bit_cast(float, (unsigned int)u << 16);
}
__device__ __forceinline__ unsigned int pk2(float lo, float hi) {
  bf16x2 v;
  v[0] = (__bf16)lo;
  v[1] = (__bf16)hi;
  return __builtin_bit_cast(unsigned int, v);
}
__device__ __forceinline__ void gll16(const void* g, void* l) {
  __builtin_amdgcn_global_load_lds(
      (const __attribute__((address_space(1))) void*)g,
      (__attribute__((address_space(3))) void*)l, 16, 0, 0);
}

// ---------------- tables + W->bf16 (r12 verbatim) ----------------
__global__ void tables_k(const int* __restrict__ idx,
                         const float* __restrict__ wr, const float* __restrict__ wi,
                         unsigned short* __restrict__ T, unsigned short* __restrict__ IT,
                         unsigned short* __restrict__ WBr, unsigned short* __restrict__ WBi) {
  int gid = blockIdx.x * blockDim.x + threadIdx.x;  // 0..262143
  const float w0 = 6.283185307179586f / (float)NL;
  {
    int row = gid >> 11, l = gid & (NL - 1);
    int m = row & 63;
    int f = idx[m];
    float s, c;
    sincosf((float)((f * l) & (NL - 1)) * w0, &s, &c);
    T[gid] = f2bf(row < 64 ? c : -s);
  }
  {
    int lp = gid >> 7, k = gid & 127;
    int m = k & 63;
    float s, c;
    sincosf((float)((m * lp) & (NL - 1)) * w0, &s, &c);
    float v = (k < 64) ? ((m == 0 ? 1.0f : 2.0f) / (float)NL) * c
                       : (m == 0 ? 0.0f : (-2.0f / (float)NL) * s);
    IT[gid] = f2bf(v);
  }
  {
    const float2* wr2 = (const float2*)wr;
    const float2* wi2 = (const float2*)wi;
    unsigned int* obr = (unsigned int*)WBr;
    unsigned int* obi = (unsigned int*)WBi;
#pragma unroll
    for (int r = 0; r < 4; ++r) {
      int j = r * 262144 + gid;
      float2 a = wr2[j];
      float2 b2 = wi2[j];
      obr[j] = pk2(a.x, a.y);
      obi[j] = pk2(b2.x, b2.y);
    }
  }
}

// ---------------- kernel A: DFT + mix, per (b,h,m-half), 512 blocks x 512 thr ----------------
// LDS: A dbuf 2x16384 @0 (rows 256B, XOR (row&7)<<4) ; B dbuf 2x16896 @32768 (264B rows)
//      post-P1: Xs [64][272B] @0 ; scr 16KB @32768
__global__ __launch_bounds__(512) void dftmix_k(const float* __restrict__ q,
                                                const unsigned short* __restrict__ T,
                                                const unsigned short* __restrict__ WBr,
                                                const unsigned short* __restrict__ WBi,
                                                unsigned short* __restrict__ O) {
  __shared__ __align__(16) char smem[66560];
  int t = threadIdx.x, lane = t & 63, wid = t >> 6;
  int h = blockIdx.x & 7, mh2 = (blockIdx.x >> 3) & 1, b = blockIdx.x >> 4;

  // ================= P1: DFT  X[64 m_ri][64 e] = T_sub * q, K=2048 =================
  {
    char* A0 = smem;
    char* A1 = smem + 16384;
    char* B0 = smem + 32768;
    char* B1 = smem + 32768 + 16896;
    const float* qb = q + ((size_t)b * NL * NH + h) * NE;  // q[b][l][h][e]
    int tm = wid & 1;           // m-group of 32 (within our 64 rows)
    int te = (wid >> 1) & 1;    // e-group of 32
    int kh = wid >> 2;          // K-half within chunk
    int eq = t & 15, ls = t >> 4;   // staging: e-quad (coalesced), l-quad 0..31
    f32x16 acc32 = {};
    f32x4 qA[4], qB[4];

    auto qload = [&](int c, f32x4* qr) {
#pragma unroll
      for (int p = 0; p < 4; ++p)
        qr[p] = *(const f32x4*)(qb + (size_t)(c * BK + ls * 4 + p) * (NH * NE) + eq * 4);
    };
    auto writesB = [&](const f32x4* qr, char* bb) {
#pragma unroll
      for (int j = 0; j < 4; ++j) {
        int e = eq * 4 + j;
        *(uint2*)(bb + e * 264 + ls * 8) =
            make_uint2(pk2(qr[0][j], qr[1][j]), pk2(qr[2][j], qr[3][j]));
      }
    };
    auto stageA = [&](char* ab, int c) {
#pragma unroll
      for (int n = 0; n < 2; ++n) {
        int lin = n * 8192 + t * 16;
        int rl = lin >> 8;                       // local row 0..63
        int grow = (rl < 32) ? (mh2 * 32 + rl) : (64 + mh2 * 32 + rl - 32);
        int colb = (lin & 255) ^ ((rl & 7) << 4);  // pre-swizzled source
        gll16((const char*)T + (size_t)grow * (NL * 2) + (size_t)c * 256 + colb, ab + lin);
      }
    };
    auto compute = [&](const char* ab, const char* bb) {
#pragma unroll
      for (int ks = 0; ks < 4; ++ks) {
        int k0 = (kh * 4 + ks) * 16;
        int e = te * 32 + (lane & 31);
        int boff = e * 264 + (k0 + (lane >> 5) * 8) * 2;
        uint2 blo = *(const uint2*)(bb + boff);
        uint2 bhi = *(const uint2*)(bb + boff + 8);
        bf16x8 bfr = __builtin_bit_cast(bf16x8, make_uint4(blo.x, blo.y, bhi.x, bhi.y));
        int row = tm * 32 + (lane & 31);
        int aoff = (row * 256 + (k0 + (lane >> 5) * 8) * 2) ^ ((row & 7) << 4);
        bf16x8 afr = __builtin_bit_cast(bf16x8, *(const us8*)(ab + aoff));
        acc32 = __builtin_amdgcn_mfma_f32_32x32x16_bf16(afr, bfr, acc32, 0, 0, 0);
      }
    };

    // prologue: A first in queue so writesB's auto-wait (q0) also drains A0
    stageA(A0, 0);
    qload(0, qA);
    qload(1, qB);
    writesB(qA, B0);   // auto vmcnt: q0 done (A0 earlier in queue -> done); q1 in flight
    asm volatile("s_waitcnt lgkmcnt(0)" ::: "memory");
    __builtin_amdgcn_s_barrier();
    // main loop: chunks c,c+1 per iter; prefetch c+2,c+3 (all valid for c<=12)
    for (int c = 0; c < 14; c += 2) {
      stageA(A1, c + 1);
      qload(c + 2, qA);
      compute(A0, B0);
      asm volatile("s_waitcnt vmcnt(4)" ::: "memory");  // drain A(c+1); keep q(c+2)
      __builtin_amdgcn_sched_barrier(0);
      __builtin_amdgcn_s_barrier();
      writesB(qB, B1);
      asm volatile("s_waitcnt lgkmcnt(0)" ::: "memory");
      __builtin_amdgcn_s_barrier();

      stageA(A0, c + 2);
      if (c + 3 < 16) qload(c + 3, qB);
      compute(A1, B1);
      asm volatile("s_waitcnt vmcnt(4)" ::: "memory");  // drain A(c+2); keep q(c+3)
      __builtin_amdgcn_sched_barrier(0);
      __builtin_amdgcn_s_barrier();
      writesB(qA, B0);
      asm volatile("s_waitcnt lgkmcnt(0)" ::: "memory");
      __builtin_amdgcn_s_barrier();
    }
    // chunk 14 (A0,B0)
    stageA(A1, 15);
    compute(A0, B0);
    asm volatile("s_waitcnt vmcnt(0)" ::: "memory");
    __builtin_amdgcn_sched_barrier(0);
    __builtin_amdgcn_s_barrier();
    writesB(qB, B1);
    asm volatile("s_waitcnt lgkmcnt(0)" ::: "memory");
    __builtin_amdgcn_s_barrier();
    // chunk 15 (A1,B1)
    compute(A1, B1);
    __syncthreads();

    // K-half merge via scratch, then Xs write [64][272B rows]
    float* scr = (float*)(smem + 32768);  // 4 tiles x 32x32 f32 = 16 KB
    int tile = wid & 3;
    if (kh == 1) {
#pragma unroll
      for (int r = 0; r < 16; ++r) {
        int row = (r & 3) + 8 * (r >> 2) + 4 * (lane >> 5);
        scr[tile * 1024 + row * 32 + (lane & 31)] = acc32[r];
      }
    }
    __syncthreads();
    if (kh == 0) {
#pragma unroll
      for (int r = 0; r < 16; ++r) {
        int row = (r & 3) + 8 * (r >> 2) + 4 * (lane >> 5);
        float v = acc32[r] + scr[tile * 1024 + row * 32 + (lane & 31)];
        int grow = tm * 32 + row;          // local m_ri (0..63)
        int gcol = te * 32 + (lane & 31);  // e
        int off = (grow * 272 + gcol * 4) ^ (((grow >> 3) & 7) << 4);
        *(float*)(smem + off) = v;
      }
    }
  }
  __syncthreads();

  // ================= P2: mix (fp32 VALU, bf16 W from L2) -> O global =================
  {
    int o = t >> 3, mq = t & 7;        // thread: 1 o, 4 m of our 32-m half
    int mgbase = mh2 * 32 + mq * 4;    // global m base
    const unsigned short* wbr = WBr + (size_t)h * 262144 + o * 64 + mgbase;
    const unsigned short* wbi = WBi + (size_t)h * 262144 + o * 64 + mgbase;
    float orr[4] = {}, oii[4] = {};
#pragma unroll 2
    for (int ib = 0; ib < 16; ++ib) {
      f32x4 xr4[4], xi4[4];
#pragma unroll
      for (int mi = 0; mi < 4; ++mi) {
        int ml = mq * 4 + mi;          // local row (re); im = 32+ml
        xr4[mi] = *(const f32x4*)(smem + ((ml * 272 + ib * 16) ^ (((ml >> 3) & 7) << 4)));
        xi4[mi] = *(const f32x4*)(smem +
                                  (((32 + ml) * 272 + ib * 16) ^ ((((32 + ml) >> 3) & 7) << 4)));
      }
      us4 wr4[4], wi4[4];
#pragma unroll
      for (int ii = 0; ii < 4; ++ii) {
        int i = ib * 4 + ii;
        wr4[ii] = *(const us4*)(wbr + (size_t)i * 4096);
        wi4[ii] = *(const us4*)(wbi + (size_t)i * 4096);
      }
#pragma unroll
      for (int ii = 0; ii < 4; ++ii)
#pragma unroll
        for (int mi = 0; mi < 4; ++mi) {
          float wrv = bf2f(wr4[ii][mi]);
          float wiv = bf2f(wi4[ii][mi]);
          orr[mi] += xr4[mi][ii] * wrv - xi4[mi][ii] * wiv;
          oii[mi] += xr4[mi][ii] * wiv + xi4[mi][ii] * wrv;
        }
    }
    unsigned short* ob = O + (((size_t)b * 8 + h) * 64 + o) * MRI;
    *(uint2*)(ob + mgbase) = make_uint2(pk2(orr[0], orr[1]), pk2(orr[2], orr[3]));
    *(uint2*)(ob + 64 + mgbase) = make_uint2(pk2(oii[0], oii[1]), pk2(oii[2], oii[3]));
  }
}

// ---------------- kernel B: iDFT out = O * IT^T (r4 verbatim) ----------------
// grid: b(32) x rowtile(4) x coltile(16); block tile [128 (h,o)][128 l'], K=128
__global__ __launch_bounds__(256) void idft_k(const unsigned short* __restrict__ O,
                                              const unsigned short* __restrict__ IT,
                                              float* __restrict__ out) {
  int bid = blockIdx.x;
  int ct = bid & 15, rt = (bid >> 4) & 3, b = bid >> 6;
  int t = threadIdx.x, lane = t & 63, wid = t >> 6;
  __shared__ unsigned short Als[128 * 128];  // O rows 256B, swizzled
  __shared__ unsigned short Bls[128 * 128];  // ITt rows 256B, swizzled
  const unsigned short* Og = O + ((size_t)b * 512 + rt * 128) * MRI;
  const unsigned short* Ig = IT + (size_t)ct * 128 * MRI;
#pragma unroll
  for (int n = 0; n < 8; ++n) {
    int lin = n * 4096 + wid * 1024 + lane * 16;
    int row = lin >> 8;
    int colb = (lin & 255) ^ ((row & 7) << 4);
    gll16((const char*)Og + (size_t)row * 256 + colb, (char*)Als + n * 4096 + wid * 1024);
  }
#pragma unroll
  for (int n = 0; n < 8; ++n) {
    int lin = n * 4096 + wid * 1024 + lane * 16;
    int row = lin >> 8;
    int colb = (lin & 255) ^ ((row & 7) << 4);
    gll16((const char*)Ig + (size_t)row * 256 + colb, (char*)Bls + n * 4096 + wid * 1024);
  }
  __syncthreads();
  int wr2 = (wid >> 1) * 64, wc = (wid & 1) * 64;
  f32x16 acc[2][2] = {};
#pragma unroll
  for (int ksp = 0; ksp < 8; ++ksp) {
    bf16x8 af[2], bfv[2];
#pragma unroll
    for (int i2 = 0; i2 < 2; ++i2) {
      int row = wr2 + i2 * 32 + (lane & 31);
      int off = ((row << 8) + (ksp << 5) + ((lane >> 5) << 4)) ^ ((row & 7) << 4);
      af[i2] = __builtin_bit_cast(bf16x8, *(const us8*)((const char*)Als + off));
      int nr = wc + i2 * 32 + (lane & 31);
      int off2 = ((nr << 8) + (ksp << 5) + ((lane >> 5) << 4)) ^ ((nr & 7) << 4);
      bfv[i2] = __builtin_bit_cast(bf16x8, *(const us8*)((const char*)Bls + off2));
    }
#pragma unroll
    for (int i2 = 0; i2 < 2; ++i2)
#pragma unroll
      for (int j2 = 0; j2 < 2; ++j2)
        acc[i2][j2] = __builtin_amdgcn_mfma_f32_32x32x16_bf16(af[i2], bfv[j2], acc[i2][j2], 0, 0, 0);
  }
  float* ob = out + ((size_t)b * 512 + rt * 128) * NL + ct * 128;
#pragma unroll
  for (int i2 = 0; i2 < 2; ++i2)
#pragma unroll
    for (int j2 = 0; j2 < 2; ++j2)
#pragma unroll
      for (int rg = 0; rg < 16; ++rg) {
        int row = wr2 + i2 * 32 + ((rg & 3) + 8 * (rg >> 2) + 4 * (lane >> 5));
        int col = wc + j2 * 32 + (lane & 31);
        ob[(size_t)row * NL + col] = acc[i2][j2][rg];
      }
}

extern "C" void kernel_launch(void* const* d_in, const int* in_sizes, int n_in,
                              void* d_out, int out_size, void* d_ws, size_t ws_size,
                              hipStream_t stream) {
  const float* q = (const float*)d_in[0];
  const float* wr = (const float*)d_in[3];
  const float* wi = (const float*)d_in[4];
  const int* idx = (const int*)d_in[5];
  float* out = (float*)d_out;
  char* ws = (char*)d_ws;

  constexpr size_t TBYTES = (size_t)MRI * NL * 2;            // 512 KB per table
  constexpr size_t WBBYTES = (size_t)NH * NE * NE * NM * 2;  // 4 MB per comp
  constexpr size_t OBYTES = (size_t)NB * NH * NE * MRI * 2;  // 4 MB
  constexpr size_t NEED = 2 * TBYTES + 2 * WBBYTES + OBYTES;
  if (ws_size < NEED) return;

  unsigned short* T = (unsigned short*)ws;
  unsigned short* IT = (unsigned short*)(ws + TBYTES);
  unsigned short* WBr = (unsigned short*)(ws + 2 * TBYTES);
  unsigned short* WBi = (unsigned short*)(ws + 2 * TBYTES + WBBYTES);
  unsigned short* O = (unsigned short*)(ws + 2 * TBYTES + 2 * WBBYTES);

  hipLaunchKernelGGL(tables_k, dim3(1024), dim3(256), 0, stream, idx, wr, wi, T, IT, WBr, WBi);
  hipLaunchKernelGGL(dftmix_k, dim3(512), dim3(512), 0, stream, q, T, WBr, WBi, O);
  hipLaunchKernelGGL(idft_k, dim3(NB * 4 * 16), dim3(256), 0, stream, O, IT, out);
}

// Round 15
// 104.499 us; speedup vs baseline: 1.0233x; 1.0233x over previous
//
#include <hip/hip_runtime.h>
#include <math.h>

#define NB 32
#define NL 2048
#define NH 8
#define NE 64
#define NM 64
#define MRI 128          // 2*NM (re stacked over im)
#define BK 128           // K per chunk
#define NCH 16           // 2048 / BK

typedef __attribute__((ext_vector_type(8))) __bf16 bf16x8;
typedef __attribute__((ext_vector_type(2))) __bf16 bf16x2;
typedef __attribute__((ext_vector_type(8))) unsigned short us8;
typedef __attribute__((ext_vector_type(4))) unsigned short us4;
typedef __attribute__((ext_vector_type(4))) float f32x4;
typedef __attribute__((ext_vector_type(16))) float f32x16;

__device__ __forceinline__ unsigned short f2bf(float x) {
  unsigned int u = __builtin_bit_cast(unsigned int, x);
  u = (u + 0x7fffu + ((u >> 16) & 1u)) >> 16;
  return (unsigned short)u;
}
__device__ __forceinline__ float bf2f(unsigned short u) {
  return __builtin_bit_cast(float, (unsigned int)u << 16);
}
__device__ __forceinline__ unsigned int pk2(float lo, float hi) {
  bf16x2 v;
  v[0] = (__bf16)lo;
  v[1] = (__bf16)hi;
  return __builtin_bit_cast(unsigned int, v);
}

// ---------------- tables + W->bf16 (r13 verbatim) ----------------
// Tf: DFT twiddles in MFMA-FRAGMENT order: [c 16][kh 2][ks 4][tm 4][lane 64][j 8] bf16.
__global__ void tables_k(const int* __restrict__ idx,
                         const float* __restrict__ wr, const float* __restrict__ wi,
                         unsigned short* __restrict__ Tf, unsigned short* __restrict__ IT,
                         unsigned short* __restrict__ WBr, unsigned short* __restrict__ WBi) {
  int gid = blockIdx.x * blockDim.x + threadIdx.x;  // 0..262143
  const float w0 = 6.283185307179586f / (float)NL;
  {
    int j = gid & 7, lane_ = (gid >> 3) & 63, tm_ = (gid >> 9) & 3;
    int ks_ = (gid >> 11) & 3, kh_ = (gid >> 13) & 1, c_ = gid >> 14;
    int row = tm_ * 32 + (lane_ & 31);
    int m = row & 63;
    int k = c_ * 128 + kh_ * 64 + ks_ * 16 + (lane_ >> 5) * 8 + j;
    int f = idx[m];
    float s, c2;
    sincosf((float)((f * k) & (NL - 1)) * w0, &s, &c2);
    Tf[gid] = f2bf(row < 64 ? c2 : -s);
  }
  {
    int lp = gid >> 7, k = gid & 127;
    int m = k & 63;
    float s, c;
    sincosf((float)((m * lp) & (NL - 1)) * w0, &s, &c);
    float v = (k < 64) ? ((m == 0 ? 1.0f : 2.0f) / (float)NL) * c
                       : (m == 0 ? 0.0f : (-2.0f / (float)NL) * s);
    IT[gid] = f2bf(v);
  }
  {
    const float2* wr2 = (const float2*)wr;
    const float2* wi2 = (const float2*)wi;
    unsigned int* obr = (unsigned int*)WBr;
    unsigned int* obi = (unsigned int*)WBi;
#pragma unroll
    for (int r = 0; r < 4; ++r) {
      int j = r * 262144 + gid;
      float2 a = wr2[j];
      float2 b2 = wi2[j];
      obr[j] = pk2(a.x, a.y);
      obi[j] = pk2(b2.x, b2.y);
    }
  }
}

// ---------------- fused per-(b,h), 256 blocks x 1024 thr ----------------
// P1: BOTH MFMA operands direct from global to registers (A: Tf fragment table,
//     B: coalesced scalar q loads). ZERO LDS, ZERO barriers in K-loop — waves
//     slip freely, 16 waves/CU hide latency.
// LDS: Xs [128][272B] @0 ; OtB [64][256B] @34816 ; scr 32KB @51200  (83968 B)
__global__ __launch_bounds__(1024) void fused_k(const float* __restrict__ q,
                                                const unsigned short* __restrict__ T,
                                                const unsigned short* __restrict__ IT,
                                                const unsigned short* __restrict__ WBr,
                                                const unsigned short* __restrict__ WBi,
                                                float* __restrict__ out) {
  __shared__ __align__(16) char smem[83968];
  int t = threadIdx.x, lane = t & 63, wid = t >> 6;
  int h = blockIdx.x & 7, b = blockIdx.x >> 3;

  // ================= P1: DFT  X = T * q  (32x32x16, K-half wave split) =================
  {
    const float* qb = q + ((size_t)b * NL * NH + h) * NE;  // q[b][l][h][e]
    int tm = wid & 3;           // m-group of 32 rows
    int te = (wid >> 2) & 1;    // e-group of 32 cols
    int kh = wid >> 3;          // K-half within chunk
    int e0 = te * 32 + (lane & 31);
    int loff = (lane >> 5) * 8;
    f32x16 acc32 = {};
    us8 arA[4], arB[4];
    bf16x8 bfA[4], bfB[4];

    auto loadA = [&](int c, us8* ar) {
#pragma unroll
      for (int ks = 0; ks < 4; ++ks)
        ar[ks] = *(const us8*)(T + ((((size_t)c * 2 + kh) * 4 + ks) * 4 + tm) * 512 + lane * 8);
    };
    auto loadB = [&](int c, bf16x8* bf) {
#pragma unroll
      for (int ks = 0; ks < 4; ++ks) {
        float tmp[8];
#pragma unroll
        for (int j = 0; j < 8; ++j)
          tmp[j] = qb[(size_t)(c * BK + kh * 64 + ks * 16 + loff + j) * (NH * NE) + e0];
        bf16x8 v;
#pragma unroll
        for (int j = 0; j < 8; ++j) v[j] = (__bf16)tmp[j];
        bf[ks] = v;
      }
    };
    auto compute = [&](const us8* ar, const bf16x8* bf) {
#pragma unroll
      for (int ks = 0; ks < 4; ++ks)
        acc32 = __builtin_amdgcn_mfma_f32_32x32x16_bf16(
            __builtin_bit_cast(bf16x8, ar[ks]), bf[ks], acc32, 0, 0, 0);
    };

    loadA(0, arA);
    loadB(0, bfA);
    loadA(1, arB);
    loadB(1, bfB);
    for (int c = 0; c < 16; c += 2) {
      compute(arA, bfA);
      if (c + 2 < 16) {
        loadA(c + 2, arA);
        loadB(c + 2, bfA);
      }
      compute(arB, bfB);
      if (c + 3 < 16) {
        loadA(c + 3, arB);
        loadB(c + 3, bfB);
      }
    }
    __syncthreads();

    // K-half merge via scratch, then Xs write (r12 verbatim)
    float* scr = (float*)(smem + 51200);  // 8 tiles x 32x32 f32 = 32 KB
    int tile = wid & 7;
    if (kh == 1) {
#pragma unroll
      for (int r = 0; r < 16; ++r) {
        int row = (r & 3) + 8 * (r >> 2) + 4 * (lane >> 5);
        scr[tile * 1024 + row * 32 + (lane & 31)] = acc32[r];
      }
    }
    __syncthreads();
    if (kh == 0) {
#pragma unroll
      for (int r = 0; r < 16; ++r) {
        int row = (r & 3) + 8 * (r >> 2) + 4 * (lane >> 5);
        float v = acc32[r] + scr[tile * 1024 + row * 32 + (lane & 31)];
        int grow = tm * 32 + row;          // m_ri
        int gcol = te * 32 + (lane & 31);  // e
        int off = (grow * 272 + gcol * 4) ^ (((grow >> 3) & 7) << 4);
        *(float*)(smem + off) = v;
      }
    }
  }
  __syncthreads();

  // ================= P2: mix (fp32 VALU, bf16 W from L2) =================
  {
    char* OtB = smem + 34816;          // [64 o][128 m_ri] bf16, 256B rows, XOR (o&7)<<4
    int o = t >> 4, mq = t & 15;       // thread: 1 o, 4 m (m = mq*4+mi)
    const unsigned short* wbr = WBr + (size_t)h * 262144 + o * 64 + mq * 4;
    const unsigned short* wbi = WBi + (size_t)h * 262144 + o * 64 + mq * 4;
    float orr[4] = {}, oii[4] = {};
#pragma unroll 2
    for (int ib = 0; ib < 16; ++ib) {
      f32x4 xr4[4], xi4[4];
#pragma unroll
      for (int mi = 0; mi < 4; ++mi) {
        int m = mq * 4 + mi;
        xr4[mi] = *(const f32x4*)(smem + ((m * 272 + ib * 16) ^ (((m >> 3) & 7) << 4)));
        xi4[mi] = *(const f32x4*)(smem + (((64 + m) * 272 + ib * 16) ^ (((m >> 3) & 7) << 4)));
      }
      us4 wr4[4], wi4[4];
#pragma unroll
      for (int ii = 0; ii < 4; ++ii) {
        int i = ib * 4 + ii;
        wr4[ii] = *(const us4*)(wbr + (size_t)i * 4096);
        wi4[ii] = *(const us4*)(wbi + (size_t)i * 4096);
      }
#pragma unroll
      for (int ii = 0; ii < 4; ++ii)
#pragma unroll
        for (int mi = 0; mi < 4; ++mi) {
          float wrv = bf2f(wr4[ii][mi]);
          float wiv = bf2f(wi4[ii][mi]);
          orr[mi] += xr4[mi][ii] * wrv - xi4[mi][ii] * wiv;
          oii[mi] += xr4[mi][ii] * wiv + xi4[mi][ii] * wrv;
        }
    }
    uint2 vr = make_uint2(pk2(orr[0], orr[1]), pk2(orr[2], orr[3]));
    uint2 vi = make_uint2(pk2(oii[0], oii[1]), pk2(oii[2], oii[3]));
    *(uint2*)(OtB + ((o * 256 + mq * 8) ^ ((o & 7) << 4))) = vr;
    *(uint2*)(OtB + ((o * 256 + 128 + mq * 8) ^ ((o & 7) << 4))) = vi;
  }
  __syncthreads();

  // ================= P3: iDFT  out = Ot * IT^T =================
  {
    const char* OtB = smem + 34816;
    bf16x8 af[2][8];
#pragma unroll
    for (int rg2 = 0; rg2 < 2; ++rg2)
#pragma unroll
      for (int ks = 0; ks < 8; ++ks) {
        int row = rg2 * 32 + (lane & 31);
        int off = (row * 256 + ks * 32 + (lane >> 5) * 16) ^ ((row & 7) << 4);
        af[rg2][ks] = __builtin_bit_cast(bf16x8, *(const us8*)(OtB + off));
      }
    float* ob = out + ((size_t)(b * 8 + h) * 64) * NL;
    int l0 = wid * 128;
    for (int ct = 0; ct < 4; ++ct) {
      int lr = l0 + ct * 32 + (lane & 31);
      f32x16 a2[2] = {};
#pragma unroll
      for (int ks = 0; ks < 8; ++ks) {
        bf16x8 bv = __builtin_bit_cast(
            bf16x8, *(const us8*)(IT + (size_t)lr * MRI + ks * 16 + (lane >> 5) * 8));
        a2[0] = __builtin_amdgcn_mfma_f32_32x32x16_bf16(af[0][ks], bv, a2[0], 0, 0, 0);
        a2[1] = __builtin_amdgcn_mfma_f32_32x32x16_bf16(af[1][ks], bv, a2[1], 0, 0, 0);
      }
#pragma unroll
      for (int rg2 = 0; rg2 < 2; ++rg2)
#pragma unroll
        for (int rg = 0; rg < 16; ++rg) {
          int row = rg2 * 32 + ((rg & 3) + 8 * (rg >> 2) + 4 * (lane >> 5));
          ob[(size_t)row * NL + lr] = a2[rg2][rg];
        }
    }
  }
}

extern "C" void kernel_launch(void* const* d_in, const int* in_sizes, int n_in,
                              void* d_out, int out_size, void* d_ws, size_t ws_size,
                              hipStream_t stream) {
  const float* q = (const float*)d_in[0];
  const float* wr = (const float*)d_in[3];
  const float* wi = (const float*)d_in[4];
  const int* idx = (const int*)d_in[5];
  float* out = (float*)d_out;
  char* ws = (char*)d_ws;

  constexpr size_t TBYTES = (size_t)MRI * NL * 2;            // 512 KB per table
  constexpr size_t WBBYTES = (size_t)NH * NE * NE * NM * 2;  // 4 MB per comp
  constexpr size_t NEED = 2 * TBYTES + 2 * WBBYTES;
  if (ws_size < NEED) return;

  unsigned short* Tf = (unsigned short*)ws;
  unsigned short* IT = (unsigned short*)(ws + TBYTES);
  unsigned short* WBr = (unsigned short*)(ws + 2 * TBYTES);
  unsigned short* WBi = (unsigned short*)(ws + 2 * TBYTES + WBBYTES);

  hipLaunchKernelGGL(tables_k, dim3(1024), dim3(256), 0, stream, idx, wr, wi, Tf, IT, WBr, WBi);
  hipLaunchKernelGGL(fused_k, dim3(NB * NH), dim3(1024), 0, stream, q, Tf, IT, WBr, WBi, out);
}

// Round 16
// 85.177 us; speedup vs baseline: 1.2554x; 1.2268x over previous
//
#include <hip/hip_runtime.h>
#include <math.h>

#define NB 32
#define NL 2048
#define NH 8
#define NE 64
#define NM 64
#define MRI 128          // 2*NM (re stacked over im)
#define BK 128           // K per chunk
#define NCH 16           // 2048 / BK

typedef __attribute__((ext_vector_type(8))) __bf16 bf16x8;
typedef __attribute__((ext_vector_type(2))) __bf16 bf16x2;
typedef __attribute__((ext_vector_type(8))) unsigned short us8;
typedef __attribute__((ext_vector_type(4))) unsigned short us4;
typedef __attribute__((ext_vector_type(4))) float f32x4;
typedef __attribute__((ext_vector_type(16))) float f32x16;

__device__ __forceinline__ unsigned short f2bf(float x) {
  unsigned int u = __builtin_bit_cast(unsigned int, x);
  u = (u + 0x7fffu + ((u >> 16) & 1u)) >> 16;
  return (unsigned short)u;
}
__device__ __forceinline__ float bf2f(unsigned short u) {
  return __builtin_bit_cast(float, (unsigned int)u << 16);
}
__device__ __forceinline__ unsigned int pk2(float lo, float hi) {
  bf16x2 v;
  v[0] = (__bf16)lo;
  v[1] = (__bf16)hi;
  return __builtin_bit_cast(unsigned int, v);
}
__device__ __forceinline__ void gll16(const void* g, void* l) {
  __builtin_amdgcn_global_load_lds(
      (const __attribute__((address_space(1))) void*)g,
      (__attribute__((address_space(3))) void*)l, 16, 0, 0);
}

// ---------------- tables + W->bf16 (r12 verbatim) ----------------
__global__ void tables_k(const int* __restrict__ idx,
                         const float* __restrict__ wr, const float* __restrict__ wi,
                         unsigned short* __restrict__ T, unsigned short* __restrict__ IT,
                         unsigned short* __restrict__ WBr, unsigned short* __restrict__ WBi) {
  int gid = blockIdx.x * blockDim.x + threadIdx.x;  // 0..262143
  const float w0 = 6.283185307179586f / (float)NL;
  {
    int row = gid >> 11, l = gid & (NL - 1);
    int m = row & 63;
    int f = idx[m];
    float s, c;
    sincosf((float)((f * l) & (NL - 1)) * w0, &s, &c);
    T[gid] = f2bf(row < 64 ? c : -s);
  }
  {
    int lp = gid >> 7, k = gid & 127;
    int m = k & 63;
    float s, c;
    sincosf((float)((m * lp) & (NL - 1)) * w0, &s, &c);
    float v = (k < 64) ? ((m == 0 ? 1.0f : 2.0f) / (float)NL) * c
                       : (m == 0 ? 0.0f : (-2.0f / (float)NL) * s);
    IT[gid] = f2bf(v);
  }
  {
    const float2* wr2 = (const float2*)wr;
    const float2* wi2 = (const float2*)wi;
    unsigned int* obr = (unsigned int*)WBr;
    unsigned int* obi = (unsigned int*)WBi;
#pragma unroll
    for (int r = 0; r < 4; ++r) {
      int j = r * 262144 + gid;
      float2 a = wr2[j];
      float2 b2 = wi2[j];
      obr[j] = pk2(a.x, a.y);
      obi[j] = pk2(b2.x, b2.y);
    }
  }
}

// ---------------- fused per-(b,h), 256 blocks x 1024 thr (r12 base) ----------------
__global__ __launch_bounds__(1024) void fused_k(const float* __restrict__ q,
                                                const unsigned short* __restrict__ T,
                                                const unsigned short* __restrict__ IT,
                                                const unsigned short* __restrict__ WBr,
                                                const unsigned short* __restrict__ WBi,
                                                float* __restrict__ out) {
  __shared__ __align__(16) char smem[99328];
  int t = threadIdx.x, lane = t & 63, wid = t >> 6;
  int h = blockIdx.x & 7, b = blockIdx.x >> 3;

  // ================= P1: DFT  X = T * q  (32x32x16 MFMA, K-half wave split) =================
  {
    char* Ab = smem;            // 2 x 32768, rows 256B, XOR (row&7)<<4
    char* B0 = smem + 65536;    // rows 264B
    char* B1 = smem + 65536 + 16896;
    const float* qb = q + ((size_t)b * NL * NH + h) * NE;  // q[b][l][h][e]
    int tm = wid & 3;           // m-group of 32 rows
    int te = (wid >> 2) & 1;    // e-group of 32 cols
    int kh = wid >> 3;          // K-half within chunk
    int eq = t & 15, lq = t >> 4;   // staging: e-quad (coalesced), l-pair
    f32x16 acc32 = {};
    f32x4 qA[2], qB[2];

    auto qload = [&](int c, f32x4* qr) {
#pragma unroll
      for (int p = 0; p < 2; ++p)
        qr[p] = *(const f32x4*)(qb + (size_t)(c * BK + lq * 2 + p) * (NH * NE) + eq * 4);
    };
    auto writesB = [&](const f32x4* qr, char* bb) {
#pragma unroll
      for (int j = 0; j < 4; ++j) {
        int e = eq * 4 + j;
        *(unsigned int*)(bb + e * 264 + lq * 4) = pk2(qr[0][j], qr[1][j]);
      }
    };
    auto stageA = [&](int bufi, int c) {
#pragma unroll
      for (int n = 0; n < 2; ++n) {
        int lin = n * 16384 + t * 16;
        int row = lin >> 8;
        int colb = (lin & 255) ^ ((row & 7) << 4);   // pre-swizzled source
        gll16((const char*)T + (size_t)row * (NL * 2) + (size_t)c * 256 + colb,
              Ab + bufi * 32768 + lin);
      }
    };
    auto compute = [&](const char* ab, const char* bb) {
#pragma unroll
      for (int ks = 0; ks < 4; ++ks) {
        int k0 = (kh * 4 + ks) * 16;
        int e = te * 32 + (lane & 31);
        int boff = e * 264 + (k0 + (lane >> 5) * 8) * 2;
        uint2 blo = *(const uint2*)(bb + boff);
        uint2 bhi = *(const uint2*)(bb + boff + 8);
        bf16x8 bfr = __builtin_bit_cast(bf16x8, make_uint4(blo.x, blo.y, bhi.x, bhi.y));
        int row = tm * 32 + (lane & 31);
        int aoff = (row * 256 + (k0 + (lane >> 5) * 8) * 2) ^ ((row & 7) << 4);
        bf16x8 afr = __builtin_bit_cast(bf16x8, *(const us8*)(ab + aoff));
        acc32 = __builtin_amdgcn_mfma_f32_32x32x16_bf16(afr, bfr, acc32, 0, 0, 0);
      }
    };

    // prologue (r12 schedule, unchanged)
    qload(0, qA);
    qload(1, qB);
    stageA(0, 0);
    writesB(qA, B0);
    asm volatile("s_waitcnt vmcnt(0)" ::: "memory");
    __builtin_amdgcn_sched_barrier(0);
    asm volatile("s_waitcnt lgkmcnt(0)" ::: "memory");
    __builtin_amdgcn_s_barrier();
    for (int c = 0; c < 14; c += 2) {
      stageA(1, c + 1);
      qload(c + 2, qA);
      compute(Ab, B0);
      asm volatile("s_waitcnt vmcnt(2)" ::: "memory");
      __builtin_amdgcn_sched_barrier(0);
      __builtin_amdgcn_s_barrier();
      writesB(qB, B1);
      asm volatile("s_waitcnt lgkmcnt(0)" ::: "memory");
      __builtin_amdgcn_s_barrier();

      stageA(0, c + 2);
      qload(c + 3, qB);
      compute(Ab + 32768, B1);
      asm volatile("s_waitcnt vmcnt(2)" ::: "memory");
      __builtin_amdgcn_sched_barrier(0);
      __builtin_amdgcn_s_barrier();
      writesB(qA, B0);
      asm volatile("s_waitcnt lgkmcnt(0)" ::: "memory");
      __builtin_amdgcn_s_barrier();
    }
    // chunk 14
    stageA(1, 15);
    compute(Ab, B0);
    asm volatile("s_waitcnt vmcnt(0)" ::: "memory");
    __builtin_amdgcn_sched_barrier(0);
    __builtin_amdgcn_s_barrier();
    writesB(qB, B1);
    asm volatile("s_waitcnt lgkmcnt(0)" ::: "memory");
    __builtin_amdgcn_s_barrier();
    // chunk 15
    compute(Ab + 32768, B1);
    __syncthreads();

    // K-half merge via scratch (over dead B-buf region), then Xs write
    float* scr = (float*)(smem + 65536);  // 8 tiles x 32x32 f32 = 32 KB
    int tile = wid & 7;
    if (kh == 1) {
#pragma unroll
      for (int r = 0; r < 16; ++r) {
        int row = (r & 3) + 8 * (r >> 2) + 4 * (lane >> 5);
        scr[tile * 1024 + row * 32 + (lane & 31)] = acc32[r];
      }
    }
    __syncthreads();
    if (kh == 0) {
#pragma unroll
      for (int r = 0; r < 16; ++r) {
        int row = (r & 3) + 8 * (r >> 2) + 4 * (lane >> 5);
        float v = acc32[r] + scr[tile * 1024 + row * 32 + (lane & 31)];
        int grow = tm * 32 + row;          // m_ri
        int gcol = te * 32 + (lane & 31);  // e
        int off = (grow * 272 + gcol * 4) ^ (((grow >> 3) & 7) << 4);
        *(float*)(smem + off) = v;
      }
    }
  }
  __syncthreads();

  // ================= P2: mix (fp32 VALU, bf16 W from L2) =================
  {
    char* OtB = smem + 34816;          // [64 o][128 m_ri] bf16, 256B rows, XOR (o&7)<<4
    int o = t >> 4, mq = t & 15;       // thread: 1 o, 4 m (m = mq*4+mi)
    const unsigned short* wbr = WBr + (size_t)h * 262144 + o * 64 + mq * 4;
    const unsigned short* wbi = WBi + (size_t)h * 262144 + o * 64 + mq * 4;
    float orr[4] = {}, oii[4] = {};
#pragma unroll 2
    for (int ib = 0; ib < 16; ++ib) {
      f32x4 xr4[4], xi4[4];
#pragma unroll
      for (int mi = 0; mi < 4; ++mi) {
        int m = mq * 4 + mi;
        xr4[mi] = *(const f32x4*)(smem + ((m * 272 + ib * 16) ^ (((m >> 3) & 7) << 4)));
        xi4[mi] = *(const f32x4*)(smem + (((64 + m) * 272 + ib * 16) ^ (((m >> 3) & 7) << 4)));
      }
      us4 wr4[4], wi4[4];
#pragma unroll
      for (int ii = 0; ii < 4; ++ii) {
        int i = ib * 4 + ii;
        wr4[ii] = *(const us4*)(wbr + (size_t)i * 4096);
        wi4[ii] = *(const us4*)(wbi + (size_t)i * 4096);
      }
#pragma unroll
      for (int ii = 0; ii < 4; ++ii)
#pragma unroll
        for (int mi = 0; mi < 4; ++mi) {
          float wrv = bf2f(wr4[ii][mi]);
          float wiv = bf2f(wi4[ii][mi]);
          orr[mi] += xr4[mi][ii] * wrv - xi4[mi][ii] * wiv;
          oii[mi] += xr4[mi][ii] * wiv + xi4[mi][ii] * wrv;
        }
    }
    uint2 vr = make_uint2(pk2(orr[0], orr[1]), pk2(orr[2], orr[3]));
    uint2 vi = make_uint2(pk2(oii[0], oii[1]), pk2(oii[2], oii[3]));
    *(uint2*)(OtB + ((o * 256 + mq * 8) ^ ((o & 7) << 4))) = vr;
    *(uint2*)(OtB + ((o * 256 + 128 + mq * 8) ^ ((o & 7) << 4))) = vi;
  }
  __syncthreads();

  // ================= P3: iDFT  out = Ot * IT^T (non-temporal stores) =================
  {
    const char* OtB = smem + 34816;
    bf16x8 af[2][8];
#pragma unroll
    for (int rg2 = 0; rg2 < 2; ++rg2)
#pragma unroll
      for (int ks = 0; ks < 8; ++ks) {
        int row = rg2 * 32 + (lane & 31);
        int off = (row * 256 + ks * 32 + (lane >> 5) * 16) ^ ((row & 7) << 4);
        af[rg2][ks] = __builtin_bit_cast(bf16x8, *(const us8*)(OtB + off));
      }
    float* ob = out + ((size_t)(b * 8 + h) * 64) * NL;
    int l0 = wid * 128;
    for (int ct = 0; ct < 4; ++ct) {
      int lr = l0 + ct * 32 + (lane & 31);
      f32x16 a2[2] = {};
#pragma unroll
      for (int ks = 0; ks < 8; ++ks) {
        bf16x8 bv = __builtin_bit_cast(
            bf16x8, *(const us8*)(IT + (size_t)lr * MRI + ks * 16 + (lane >> 5) * 8));
        a2[0] = __builtin_amdgcn_mfma_f32_32x32x16_bf16(af[0][ks], bv, a2[0], 0, 0, 0);
        a2[1] = __builtin_amdgcn_mfma_f32_32x32x16_bf16(af[1][ks], bv, a2[1], 0, 0, 0);
      }
#pragma unroll
      for (int rg2 = 0; rg2 < 2; ++rg2)
#pragma unroll
        for (int rg = 0; rg < 16; ++rg) {
          int row = rg2 * 32 + ((rg & 3) + 8 * (rg >> 2) + 4 * (lane >> 5));
          __builtin_nontemporal_store(a2[rg2][rg], &ob[(size_t)row * NL + lr]);
        }
    }
  }
}

extern "C" void kernel_launch(void* const* d_in, const int* in_sizes, int n_in,
                              void* d_out, int out_size, void* d_ws, size_t ws_size,
                              hipStream_t stream) {
  const float* q = (const float*)d_in[0];
  const float* wr = (const float*)d_in[3];
  const float* wi = (const float*)d_in[4];
  const int* idx = (const int*)d_in[5];
  float* out = (float*)d_out;
  char* ws = (char*)d_ws;

  constexpr size_t TBYTES = (size_t)MRI * NL * 2;            // 512 KB per table
  constexpr size_t WBBYTES = (size_t)NH * NE * NE * NM * 2;  // 4 MB per comp
  constexpr size_t NEED = 2 * TBYTES + 2 * WBBYTES;
  if (ws_size < NEED) return;

  unsigned short* T = (unsigned short*)ws;
  unsigned short* IT = (unsigned short*)(ws + TBYTES);
  unsigned short* WBr = (unsigned short*)(ws + 2 * TBYTES);
  unsigned short* WBi = (unsigned short*)(ws + 2 * TBYTES + WBBYTES);

  hipLaunchKernelGGL(tables_k, dim3(1024), dim3(256), 0, stream, idx, wr, wi, T, IT, WBr, WBi);
  hipLaunchKernelGGL(fused_k, dim3(NB * NH), dim3(1024), 0, stream, q, T, IT, WBr, WBi, out);
}

// Round 17
// 84.334 us; speedup vs baseline: 1.2679x; 1.0100x over previous
//
#include <hip/hip_runtime.h>
#include <math.h>

#define NB 32
#define NL 2048
#define NH 8
#define NE 64
#define NM 64
#define MRI 128          // 2*NM (re stacked over im)
#define BK 256           // K per chunk
#define NCH 8            // 2048 / BK

typedef __attribute__((ext_vector_type(8))) __bf16 bf16x8;
typedef __attribute__((ext_vector_type(2))) __bf16 bf16x2;
typedef __attribute__((ext_vector_type(8))) unsigned short us8;
typedef __attribute__((ext_vector_type(4))) unsigned short us4;
typedef __attribute__((ext_vector_type(4))) float f32x4;
typedef __attribute__((ext_vector_type(16))) float f32x16;

__device__ __forceinline__ unsigned short f2bf(float x) {
  unsigned int u = __builtin_bit_cast(unsigned int, x);
  u = (u + 0x7fffu + ((u >> 16) & 1u)) >> 16;
  return (unsigned short)u;
}
__device__ __forceinline__ float bf2f(unsigned short u) {
  return __builtin_bit_cast(float, (unsigned int)u << 16);
}
__device__ __forceinline__ unsigned int pk2(float lo, float hi) {
  bf16x2 v;
  v[0] = (__bf16)lo;
  v[1] = (__bf16)hi;
  return __builtin_bit_cast(unsigned int, v);
}

// ---------------- tables + W->bf16 ----------------
// Tf: DFT twiddles in MFMA-FRAGMENT order for BK=256:
//     [c 8][kh 2][ks 8][tm 4][lane 64][j 8] bf16.
//     row = tm*32+(lane&31); k = c*256 + kh*128 + ks*16 + (lane>>5)*8 + j;
//     val = (row<64 ? cos : -sin)(2pi*f_{row&63}*k/L).
// IT [2048][128] bf16 : col m = s_m*cos(2pi*m*l'/L); col 64+m = -s_m*sin(...)
// WB r/i: w_real/imag [h][i][o][m] -> bf16 (W[h]=1MB bf16 -> L2-resident/XCD)
__global__ void tables_k(const int* __restrict__ idx,
                         const float* __restrict__ wr, const float* __restrict__ wi,
                         unsigned short* __restrict__ Tf, unsigned short* __restrict__ IT,
                         unsigned short* __restrict__ WBr, unsigned short* __restrict__ WBi) {
  int gid = blockIdx.x * blockDim.x + threadIdx.x;  // 0..262143
  const float w0 = 6.283185307179586f / (float)NL;
  {
    int j = gid & 7, lane_ = (gid >> 3) & 63, tm_ = (gid >> 9) & 3;
    int ks_ = (gid >> 11) & 7, kh_ = (gid >> 14) & 1, c_ = gid >> 15;
    int row = tm_ * 32 + (lane_ & 31);
    int m = row & 63;
    int k = c_ * 256 + kh_ * 128 + ks_ * 16 + (lane_ >> 5) * 8 + j;
    int f = idx[m];
    float s, c2;
    sincosf((float)((f * k) & (NL - 1)) * w0, &s, &c2);
    Tf[gid] = f2bf(row < 64 ? c2 : -s);
  }
  {
    int lp = gid >> 7, k = gid & 127;
    int m = k & 63;
    float s, c;
    sincosf((float)((m * lp) & (NL - 1)) * w0, &s, &c);
    float v = (k < 64) ? ((m == 0 ? 1.0f : 2.0f) / (float)NL) * c
                       : (m == 0 ? 0.0f : (-2.0f / (float)NL) * s);
    IT[gid] = f2bf(v);
  }
  {
    const float2* wr2 = (const float2*)wr;
    const float2* wi2 = (const float2*)wi;
    unsigned int* obr = (unsigned int*)WBr;
    unsigned int* obi = (unsigned int*)WBi;
#pragma unroll
    for (int r = 0; r < 4; ++r) {
      int j = r * 262144 + gid;
      float2 a = wr2[j];
      float2 b2 = wi2[j];
      obr[j] = pk2(a.x, a.y);
      obi[j] = pk2(b2.x, b2.y);
    }
  }
}

// ---------------- fused per-(b,h), 256 blocks x 1024 thr ----------------
// P1: BK=256 (8 chunks, 16 barrier drains vs r12's 32). A entirely in registers
//     (Tf fragment table, 2-deep ring, coalesced 1KB/wave loads from L2).
//     B (q) dbuf LDS [64 e][512B rows], granule swizzle (e&31)<<4 -> conflict-free
//     on BOTH packed writes and b128 reads.
// LDS: Xs [128][272B] @0 ; OtB [64][256B] @34816 ; B0/B1 2x32768 @51200 (peak 114KB)
//      scr 32KB @51200 (post-P1, over dead B0)
__global__ __launch_bounds__(1024) void fused_k(const float* __restrict__ q,
                                                const unsigned short* __restrict__ T,
                                                const unsigned short* __restrict__ IT,
                                                const unsigned short* __restrict__ WBr,
                                                const unsigned short* __restrict__ WBi,
                                                float* __restrict__ out) {
  __shared__ __align__(16) char smem[116736];
  int t = threadIdx.x, lane = t & 63, wid = t >> 6;
  int h = blockIdx.x & 7, b = blockIdx.x >> 3;

  // ================= P1: DFT  X = T * q  (32x32x16, K-half wave split) =================
  {
    char* B0 = smem + 51200;
    char* B1 = smem + 51200 + 32768;
    const float* qb = q + ((size_t)b * NL * NH + h) * NE;  // q[b][l][h][e]
    int tm = wid & 3;           // m-group of 32 rows
    int te = (wid >> 2) & 1;    // e-group of 32 cols
    int kh = wid >> 3;          // K-half within chunk (0: k 0-127, 1: k 128-255)
    int eq = t & 15, lq = t >> 4;   // staging: e-quad (coalesced), l-quad 0..63
    f32x16 acc32 = {};
    f32x4 qA[4], qB[4];
    us8 arA[8], arB[8];

    auto qload = [&](int c, f32x4* qr) {
#pragma unroll
      for (int p = 0; p < 4; ++p)
        qr[p] = *(const f32x4*)(qb + (size_t)(c * BK + lq * 4 + p) * (NH * NE) + eq * 4);
    };
    auto writesB = [&](const f32x4* qr, char* bb) {
#pragma unroll
      for (int j = 0; j < 4; ++j) {
        int e = eq * 4 + j;
        int sw = (e & 31) << 4;
        *(uint2*)(bb + ((e * 512 + lq * 8) ^ sw)) =
            make_uint2(pk2(qr[0][j], qr[1][j]), pk2(qr[2][j], qr[3][j]));
      }
    };
    auto loadA = [&](int c, us8* ar) {
#pragma unroll
      for (int ks = 0; ks < 8; ++ks)
        ar[ks] = *(const us8*)(T + ((((size_t)c * 2 + kh) * 8 + ks) * 4 + tm) * 512 + lane * 8);
    };
    auto compute = [&](const us8* ar, const char* bb) {
#pragma unroll
      for (int ks = 0; ks < 8; ++ks) {
        int e = te * 32 + (lane & 31);
        int kbyte = (kh * 128 + ks * 16 + (lane >> 5) * 8) * 2;
        int boff = (e * 512 + kbyte) ^ ((e & 31) << 4);
        bf16x8 bfr = __builtin_bit_cast(bf16x8, *(const us8*)(bb + boff));
        acc32 = __builtin_amdgcn_mfma_f32_32x32x16_bf16(
            __builtin_bit_cast(bf16x8, ar[ks]), bfr, acc32, 0, 0, 0);
      }
    };

    // prologue
    qload(0, qA);
    qload(1, qB);
    loadA(0, arA);
    writesB(qA, B0);   // auto vmcnt on qA; q1/arA stay in flight
    asm volatile("s_waitcnt lgkmcnt(0)" ::: "memory");
    __builtin_amdgcn_s_barrier();
    // main loop: 2 chunks per iter (4 iters), two-barrier skeleton, A in regs
    for (int c = 0; c < NCH; c += 2) {
      loadA(c + 1, arB);                     // in flight during chunk c
      if (c + 2 < NCH) qload(c + 2, qA);
      compute(arA, B0);                      // per-wave auto waits only
      __builtin_amdgcn_s_barrier();          // B0 readers done
      writesB(qB, B1);                       // q(c+1), loaded 2 chunks ago
      asm volatile("s_waitcnt lgkmcnt(0)" ::: "memory");
      __builtin_amdgcn_s_barrier();
      if (c + 2 < NCH) loadA(c + 2, arA);
      if (c + 3 < NCH) qload(c + 3, qB);
      compute(arB, B1);
      if (c + 2 < NCH) {
        __builtin_amdgcn_s_barrier();        // B1 readers done
        writesB(qA, B0);
        asm volatile("s_waitcnt lgkmcnt(0)" ::: "memory");
        __builtin_amdgcn_s_barrier();
      }
    }
    __syncthreads();

    // K-half merge via scratch (over dead B0), then Xs write
    float* scr = (float*)(smem + 51200);  // 8 tiles x 32x32 f32 = 32 KB
    int tile = wid & 7;
    if (kh == 1) {
#pragma unroll
      for (int r = 0; r < 16; ++r) {
        int row = (r & 3) + 8 * (r >> 2) + 4 * (lane >> 5);
        scr[tile * 1024 + row * 32 + (lane & 31)] = acc32[r];
      }
    }
    __syncthreads();
    if (kh == 0) {
#pragma unroll
      for (int r = 0; r < 16; ++r) {
        int row = (r & 3) + 8 * (r >> 2) + 4 * (lane >> 5);
        float v = acc32[r] + scr[tile * 1024 + row * 32 + (lane & 31)];
        int grow = tm * 32 + row;          // m_ri
        int gcol = te * 32 + (lane & 31);  // e
        int off = (grow * 272 + gcol * 4) ^ (((grow >> 3) & 7) << 4);
        *(float*)(smem + off) = v;
      }
    }
  }
  __syncthreads();

  // ================= P2: mix (fp32 VALU, bf16 W from L2) =================
  {
    char* OtB = smem + 34816;          // [64 o][128 m_ri] bf16, 256B rows, XOR (o&7)<<4
    int o = t >> 4, mq = t & 15;       // thread: 1 o, 4 m (m = mq*4+mi)
    const unsigned short* wbr = WBr + (size_t)h * 262144 + o * 64 + mq * 4;
    const unsigned short* wbi = WBi + (size_t)h * 262144 + o * 64 + mq * 4;
    float orr[4] = {}, oii[4] = {};
#pragma unroll 2
    for (int ib = 0; ib < 16; ++ib) {
      f32x4 xr4[4], xi4[4];
#pragma unroll
      for (int mi = 0; mi < 4; ++mi) {
        int m = mq * 4 + mi;
        xr4[mi] = *(const f32x4*)(smem + ((m * 272 + ib * 16) ^ (((m >> 3) & 7) << 4)));
        xi4[mi] = *(const f32x4*)(smem + (((64 + m) * 272 + ib * 16) ^ (((m >> 3) & 7) << 4)));
      }
      us4 wr4[4], wi4[4];
#pragma unroll
      for (int ii = 0; ii < 4; ++ii) {
        int i = ib * 4 + ii;
        wr4[ii] = *(const us4*)(wbr + (size_t)i * 4096);
        wi4[ii] = *(const us4*)(wbi + (size_t)i * 4096);
      }
#pragma unroll
      for (int ii = 0; ii < 4; ++ii)
#pragma unroll
        for (int mi = 0; mi < 4; ++mi) {
          float wrv = bf2f(wr4[ii][mi]);
          float wiv = bf2f(wi4[ii][mi]);
          orr[mi] += xr4[mi][ii] * wrv - xi4[mi][ii] * wiv;
          oii[mi] += xr4[mi][ii] * wiv + xi4[mi][ii] * wrv;
        }
    }
    uint2 vr = make_uint2(pk2(orr[0], orr[1]), pk2(orr[2], orr[3]));
    uint2 vi = make_uint2(pk2(oii[0], oii[1]), pk2(oii[2], oii[3]));
    *(uint2*)(OtB + ((o * 256 + mq * 8) ^ ((o & 7) << 4))) = vr;
    *(uint2*)(OtB + ((o * 256 + 128 + mq * 8) ^ ((o & 7) << 4))) = vi;
  }
  __syncthreads();

  // ================= P3: iDFT  out = Ot * IT^T (nt stores) =================
  {
    const char* OtB = smem + 34816;
    bf16x8 af[2][8];
#pragma unroll
    for (int rg2 = 0; rg2 < 2; ++rg2)
#pragma unroll
      for (int ks = 0; ks < 8; ++ks) {
        int row = rg2 * 32 + (lane & 31);
        int off = (row * 256 + ks * 32 + (lane >> 5) * 16) ^ ((row & 7) << 4);
        af[rg2][ks] = __builtin_bit_cast(bf16x8, *(const us8*)(OtB + off));
      }
    float* ob = out + ((size_t)(b * 8 + h) * 64) * NL;
    int l0 = wid * 128;
    for (int ct = 0; ct < 4; ++ct) {
      int lr = l0 + ct * 32 + (lane & 31);
      f32x16 a2[2] = {};
#pragma unroll
      for (int ks = 0; ks < 8; ++ks) {
        bf16x8 bv = __builtin_bit_cast(
            bf16x8, *(const us8*)(IT + (size_t)lr * MRI + ks * 16 + (lane >> 5) * 8));
        a2[0] = __builtin_amdgcn_mfma_f32_32x32x16_bf16(af[0][ks], bv, a2[0], 0, 0, 0);
        a2[1] = __builtin_amdgcn_mfma_f32_32x32x16_bf16(af[1][ks], bv, a2[1], 0, 0, 0);
      }
#pragma unroll
      for (int rg2 = 0; rg2 < 2; ++rg2)
#pragma unroll
        for (int rg = 0; rg < 16; ++rg) {
          int row = rg2 * 32 + ((rg & 3) + 8 * (rg >> 2) + 4 * (lane >> 5));
          __builtin_nontemporal_store(a2[rg2][rg], &ob[(size_t)row * NL + lr]);
        }
    }
  }
}

extern "C" void kernel_launch(void* const* d_in, const int* in_sizes, int n_in,
                              void* d_out, int out_size, void* d_ws, size_t ws_size,
                              hipStream_t stream) {
  const float* q = (const float*)d_in[0];
  const float* wr = (const float*)d_in[3];
  const float* wi = (const float*)d_in[4];
  const int* idx = (const int*)d_in[5];
  float* out = (float*)d_out;
  char* ws = (char*)d_ws;

  constexpr size_t TBYTES = (size_t)MRI * NL * 2;            // 512 KB per table
  constexpr size_t WBBYTES = (size_t)NH * NE * NE * NM * 2;  // 4 MB per comp
  constexpr size_t NEED = 2 * TBYTES + 2 * WBBYTES;
  if (ws_size < NEED) return;

  unsigned short* Tf = (unsigned short*)ws;
  unsigned short* IT = (unsigned short*)(ws + TBYTES);
  unsigned short* WBr = (unsigned short*)(ws + 2 * TBYTES);
  unsigned short* WBi = (unsigned short*)(ws + 2 * TBYTES + WBBYTES);

  hipLaunchKernelGGL(tables_k, dim3(1024), dim3(256), 0, stream, idx, wr, wi, Tf, IT, WBr, WBi);
  hipLaunchKernelGGL(fused_k, dim3(NB * NH), dim3(1024), 0, stream, q, Tf, IT, WBr, WBi, out);
}

// Round 18
// 82.609 us; speedup vs baseline: 1.2944x; 1.0209x over previous
//
#include <hip/hip_runtime.h>
#include <math.h>

#define NB 32
#define NL 2048
#define NH 8
#define NE 64
#define NM 64
#define MRI 128          // 2*NM (re stacked over im)
#define BK 128           // K per chunk
#define NCH 16           // 2048 / BK

typedef __attribute__((ext_vector_type(8))) __bf16 bf16x8;
typedef __attribute__((ext_vector_type(2))) __bf16 bf16x2;
typedef __attribute__((ext_vector_type(8))) unsigned short us8;
typedef __attribute__((ext_vector_type(4))) unsigned short us4;
typedef __attribute__((ext_vector_type(4))) float f32x4;
typedef __attribute__((ext_vector_type(16))) float f32x16;

__device__ __forceinline__ unsigned short f2bf(float x) {
  unsigned int u = __builtin_bit_cast(unsigned int, x);
  u = (u + 0x7fffu + ((u >> 16) & 1u)) >> 16;
  return (unsigned short)u;
}
__device__ __forceinline__ float bf2f(unsigned short u) {
  return __builtin_bit_cast(float, (unsigned int)u << 16);
}
__device__ __forceinline__ unsigned int pk2(float lo, float hi) {
  bf16x2 v;
  v[0] = (__bf16)lo;
  v[1] = (__bf16)hi;
  return __builtin_bit_cast(unsigned int, v);
}

// ---------------- tables + W->bf16 (r13 verbatim, bit-exact verified) ----------------
// Tf: DFT twiddles in MFMA-FRAGMENT order: [c 16][kh 2][ks 4][tm 4][lane 64][j 8] bf16.
__global__ void tables_k(const int* __restrict__ idx,
                         const float* __restrict__ wr, const float* __restrict__ wi,
                         unsigned short* __restrict__ Tf, unsigned short* __restrict__ IT,
                         unsigned short* __restrict__ WBr, unsigned short* __restrict__ WBi) {
  int gid = blockIdx.x * blockDim.x + threadIdx.x;  // 0..262143
  const float w0 = 6.283185307179586f / (float)NL;
  {
    int j = gid & 7, lane_ = (gid >> 3) & 63, tm_ = (gid >> 9) & 3;
    int ks_ = (gid >> 11) & 3, kh_ = (gid >> 13) & 1, c_ = gid >> 14;
    int row = tm_ * 32 + (lane_ & 31);
    int m = row & 63;
    int k = c_ * 128 + kh_ * 64 + ks_ * 16 + (lane_ >> 5) * 8 + j;
    int f = idx[m];
    float s, c2;
    sincosf((float)((f * k) & (NL - 1)) * w0, &s, &c2);
    Tf[gid] = f2bf(row < 64 ? c2 : -s);
  }
  {
    int lp = gid >> 7, k = gid & 127;
    int m = k & 63;
    float s, c;
    sincosf((float)((m * lp) & (NL - 1)) * w0, &s, &c);
    float v = (k < 64) ? ((m == 0 ? 1.0f : 2.0f) / (float)NL) * c
                       : (m == 0 ? 0.0f : (-2.0f / (float)NL) * s);
    IT[gid] = f2bf(v);
  }
  {
    const float2* wr2 = (const float2*)wr;
    const float2* wi2 = (const float2*)wi;
    unsigned int* obr = (unsigned int*)WBr;
    unsigned int* obi = (unsigned int*)WBi;
#pragma unroll
    for (int r = 0; r < 4; ++r) {
      int j = r * 262144 + gid;
      float2 a = wr2[j];
      float2 b2 = wi2[j];
      obr[j] = pk2(a.x, a.y);
      obi[j] = pk2(b2.x, b2.y);
    }
  }
}

// ---------------- fused per-(b,h), 256 blocks x 1024 thr ----------------
// P1: A in PINNED register ring (sched_barrier keeps prefetch issued 1 chunk
//     ahead; per-wave counted vmcnt at use). B (q) in 3-buffer LDS rotation ->
//     ONE lgkm-only barrier per chunk, no vmcnt drain anywhere in the loop.
// LDS: Xs [128][272B] @0 ; B bufs 3x16896 @34816 ; scr 32KB @34816 (post-P1);
//      OtB [64][256B] @67584.  Total 85504 B.
__global__ __launch_bounds__(1024) void fused_k(const float* __restrict__ q,
                                                const unsigned short* __restrict__ T,
                                                const unsigned short* __restrict__ IT,
                                                const unsigned short* __restrict__ WBr,
                                                const unsigned short* __restrict__ WBi,
                                                float* __restrict__ out) {
  __shared__ __align__(16) char smem[85504];
  int t = threadIdx.x, lane = t & 63, wid = t >> 6;
  int h = blockIdx.x & 7, b = blockIdx.x >> 3;

  // ================= P1: DFT  X = T * q  (32x32x16, K-half wave split) =================
  {
    char* bC = smem + 34816;            // chunk c (being read)
    char* bN = smem + 34816 + 16896;    // chunk c+1 (being written)
    char* bX = smem + 34816 + 33792;    // chunk c+2 (free)
    const float* qb = q + ((size_t)b * NL * NH + h) * NE;  // q[b][l][h][e]
    int tm = wid & 3;           // m-group of 32 rows
    int te = (wid >> 2) & 1;    // e-group of 32 cols
    int kh = wid >> 3;          // K-half within chunk
    int eq = t & 15, lq = t >> 4;   // staging: e-quad (coalesced), l-pair
    f32x16 acc32 = {};
    f32x4 qA[2], qB[2];
    us8 arA[4], arB[4];

    auto qload = [&](int c, f32x4* qr) {
#pragma unroll
      for (int p = 0; p < 2; ++p)
        qr[p] = *(const f32x4*)(qb + (size_t)(c * BK + lq * 2 + p) * (NH * NE) + eq * 4);
    };
    auto writesB = [&](const f32x4* qr, char* bb) {
#pragma unroll
      for (int j = 0; j < 4; ++j) {
        int e = eq * 4 + j;
        *(unsigned int*)(bb + e * 264 + lq * 4) = pk2(qr[0][j], qr[1][j]);
      }
    };
    auto loadA = [&](int c, us8* ar) {
#pragma unroll
      for (int ks = 0; ks < 4; ++ks)
        ar[ks] = *(const us8*)(T + ((((size_t)c * 2 + kh) * 4 + ks) * 4 + tm) * 512 + lane * 8);
    };
    auto compute = [&](const us8* ar, const char* bb) {
#pragma unroll
      for (int ks = 0; ks < 4; ++ks) {
        int k0 = (kh * 4 + ks) * 16;
        int e = te * 32 + (lane & 31);
        int boff = e * 264 + (k0 + (lane >> 5) * 8) * 2;
        uint2 blo = *(const uint2*)(bb + boff);
        uint2 bhi = *(const uint2*)(bb + boff + 8);
        bf16x8 bfr = __builtin_bit_cast(bf16x8, make_uint4(blo.x, blo.y, bhi.x, bhi.y));
        acc32 = __builtin_amdgcn_mfma_f32_32x32x16_bf16(
            __builtin_bit_cast(bf16x8, ar[ks]), bfr, acc32, 0, 0, 0);
      }
    };
    auto rot = [&]() {
      char* tmp = bC;
      bC = bN;
      bN = bX;
      bX = tmp;
    };

    // prologue
    qload(0, qA);
    qload(1, qB);
    loadA(0, arA);
    writesB(qA, bC);   // per-wave auto vmcnt on qA; qB/arA stay in flight
    asm volatile("s_waitcnt lgkmcnt(0)" ::: "memory");
    __builtin_amdgcn_s_barrier();
    // main loop: ONE lgkm-barrier per chunk; prefetches pinned above compute
    for (int c = 0; c < NCH; c += 2) {
      loadA(c + 1, arB);
      if (c + 2 < NCH) qload(c + 2, qA);
      __builtin_amdgcn_sched_barrier(0);     // pin prefetch issue above compute
      compute(arA, bC);
      writesB(qB, bN);                       // q(c+1), loaded one chunk ago
      asm volatile("s_waitcnt lgkmcnt(0)" ::: "memory");
      __builtin_amdgcn_s_barrier();
      rot();
      if (c + 2 < NCH) loadA(c + 2, arA);
      if (c + 3 < NCH) qload(c + 3, qB);
      __builtin_amdgcn_sched_barrier(0);
      compute(arB, bC);
      if (c + 2 < NCH) {
        writesB(qA, bN);
        asm volatile("s_waitcnt lgkmcnt(0)" ::: "memory");
        __builtin_amdgcn_s_barrier();
      }
      rot();
    }
    __syncthreads();

    // K-half merge via scratch (over dead B bufs), then Xs write
    float* scr = (float*)(smem + 34816);  // 8 tiles x 32x32 f32 = 32 KB
    int tile = wid & 7;
    if (kh == 1) {
#pragma unroll
      for (int r = 0; r < 16; ++r) {
        int row = (r & 3) + 8 * (r >> 2) + 4 * (lane >> 5);
        scr[tile * 1024 + row * 32 + (lane & 31)] = acc32[r];
      }
    }
    __syncthreads();
    if (kh == 0) {
#pragma unroll
      for (int r = 0; r < 16; ++r) {
        int row = (r & 3) + 8 * (r >> 2) + 4 * (lane >> 5);
        float v = acc32[r] + scr[tile * 1024 + row * 32 + (lane & 31)];
        int grow = tm * 32 + row;          // m_ri
        int gcol = te * 32 + (lane & 31);  // e
        int off = (grow * 272 + gcol * 4) ^ (((grow >> 3) & 7) << 4);
        *(float*)(smem + off) = v;
      }
    }
  }
  __syncthreads();

  // ================= P2: mix (fp32 VALU, bf16 W from L2) =================
  {
    char* OtB = smem + 67584;          // [64 o][128 m_ri] bf16, 256B rows, XOR (o&7)<<4
    int o = t >> 4, mq = t & 15;       // thread: 1 o, 4 m (m = mq*4+mi)
    const unsigned short* wbr = WBr + (size_t)h * 262144 + o * 64 + mq * 4;
    const unsigned short* wbi = WBi + (size_t)h * 262144 + o * 64 + mq * 4;
    float orr[4] = {}, oii[4] = {};
#pragma unroll 2
    for (int ib = 0; ib < 16; ++ib) {
      f32x4 xr4[4], xi4[4];
#pragma unroll
      for (int mi = 0; mi < 4; ++mi) {
        int m = mq * 4 + mi;
        xr4[mi] = *(const f32x4*)(smem + ((m * 272 + ib * 16) ^ (((m >> 3) & 7) << 4)));
        xi4[mi] = *(const f32x4*)(smem + (((64 + m) * 272 + ib * 16) ^ (((m >> 3) & 7) << 4)));
      }
      us4 wr4[4], wi4[4];
#pragma unroll
      for (int ii = 0; ii < 4; ++ii) {
        int i = ib * 4 + ii;
        wr4[ii] = *(const us4*)(wbr + (size_t)i * 4096);
        wi4[ii] = *(const us4*)(wbi + (size_t)i * 4096);
      }
#pragma unroll
      for (int ii = 0; ii < 4; ++ii)
#pragma unroll
        for (int mi = 0; mi < 4; ++mi) {
          float wrv = bf2f(wr4[ii][mi]);
          float wiv = bf2f(wi4[ii][mi]);
          orr[mi] += xr4[mi][ii] * wrv - xi4[mi][ii] * wiv;
          oii[mi] += xr4[mi][ii] * wiv + xi4[mi][ii] * wrv;
        }
    }
    uint2 vr = make_uint2(pk2(orr[0], orr[1]), pk2(orr[2], orr[3]));
    uint2 vi = make_uint2(pk2(oii[0], oii[1]), pk2(oii[2], oii[3]));
    *(uint2*)(OtB + ((o * 256 + mq * 8) ^ ((o & 7) << 4))) = vr;
    *(uint2*)(OtB + ((o * 256 + 128 + mq * 8) ^ ((o & 7) << 4))) = vi;
  }
  __syncthreads();

  // ================= P3: iDFT  out = Ot * IT^T (nt stores) =================
  {
    const char* OtB = smem + 67584;
    bf16x8 af[2][8];
#pragma unroll
    for (int rg2 = 0; rg2 < 2; ++rg2)
#pragma unroll
      for (int ks = 0; ks < 8; ++ks) {
        int row = rg2 * 32 + (lane & 31);
        int off = (row * 256 + ks * 32 + (lane >> 5) * 16) ^ ((row & 7) << 4);
        af[rg2][ks] = __builtin_bit_cast(bf16x8, *(const us8*)(OtB + off));
      }
    float* ob = out + ((size_t)(b * 8 + h) * 64) * NL;
    int l0 = wid * 128;
    for (int ct = 0; ct < 4; ++ct) {
      int lr = l0 + ct * 32 + (lane & 31);
      f32x16 a2[2] = {};
#pragma unroll
      for (int ks = 0; ks < 8; ++ks) {
        bf16x8 bv = __builtin_bit_cast(
            bf16x8, *(const us8*)(IT + (size_t)lr * MRI + ks * 16 + (lane >> 5) * 8));
        a2[0] = __builtin_amdgcn_mfma_f32_32x32x16_bf16(af[0][ks], bv, a2[0], 0, 0, 0);
        a2[1] = __builtin_amdgcn_mfma_f32_32x32x16_bf16(af[1][ks], bv, a2[1], 0, 0, 0);
      }
#pragma unroll
      for (int rg2 = 0; rg2 < 2; ++rg2)
#pragma unroll
        for (int rg = 0; rg < 16; ++rg) {
          int row = rg2 * 32 + ((rg & 3) + 8 * (rg >> 2) + 4 * (lane >> 5));
          __builtin_nontemporal_store(a2[rg2][rg], &ob[(size_t)row * NL + lr]);
        }
    }
  }
}

extern "C" void kernel_launch(void* const* d_in, const int* in_sizes, int n_in,
                              void* d_out, int out_size, void* d_ws, size_t ws_size,
                              hipStream_t stream) {
  const float* q = (const float*)d_in[0];
  const float* wr = (const float*)d_in[3];
  const float* wi = (const float*)d_in[4];
  const int* idx = (const int*)d_in[5];
  float* out = (float*)d_out;
  char* ws = (char*)d_ws;

  constexpr size_t TBYTES = (size_t)MRI * NL * 2;            // 512 KB per table
  constexpr size_t WBBYTES = (size_t)NH * NE * NE * NM * 2;  // 4 MB per comp
  constexpr size_t NEED = 2 * TBYTES + 2 * WBBYTES;
  if (ws_size < NEED) return;

  unsigned short* Tf = (unsigned short*)ws;
  unsigned short* IT = (unsigned short*)(ws + TBYTES);
  unsigned short* WBr = (unsigned short*)(ws + 2 * TBYTES);
  unsigned short* WBi = (unsigned short*)(ws + 2 * TBYTES + WBBYTES);

  hipLaunchKernelGGL(tables_k, dim3(1024), dim3(256), 0, stream, idx, wr, wi, Tf, IT, WBr, WBi);
  hipLaunchKernelGGL(fused_k, dim3(NB * NH), dim3(1024), 0, stream, q, Tf, IT, WBr, WBi, out);
}